// Round 3
// baseline (4538.797 us; speedup 1.0000x reference)
//
#include <hip/hip_runtime.h>
#include <hip/hip_bf16.h>
#include <cstdint>
#include <cstddef>

#define NDIMC   128
#define DEPTHC  6
#define NPASSESC 4
#define NNODES  50000
#define NEDGES  800000
#define NODEIN  5
#define LNEPS   1e-5f

// ---------------------------------------------------------------------------
// ws layout (bytes) — ~224 MiB, below proven-safe 256,000,004
#define H_OFF    0ull                     // h:  50000*128*4  = 25.6 MB fp32
#define E_OFF    25600000ull              // e:  800000*128*2 = 204.8 MB bf16 (CSR-slot order)
#define PW_OFF   230400000ull             // packed weights: 4 * 196,608 B bf16
#define FLAG_OFF 231186432ull
#define DEG_OFF  231186436ull             // 50001 int
#define RS_OFF   231386440ull             // rowstart: 50001 int
#define CUR_OFF  231586444ull             // cursor:   50000 int
#define EIDX_OFF 231786444ull             // eidx:     800000 int -> ends 234,986,444
#define PWMAT    98304                    // shorts per packed matrix (6*2*8192)

typedef __attribute__((ext_vector_type(8))) short mgn_sh8;
typedef __attribute__((ext_vector_type(4))) float mgn_f32x4;

// ---------------------------------------------------------------------------
__device__ __forceinline__ unsigned mgn_bf16bits(float f) {
    unsigned x = __float_as_uint(f);
    return (x + 0x7fffu + ((x >> 16) & 1u)) >> 16;   // RNE
}
__device__ __forceinline__ unsigned mgn_pk(float a, float b) {
    __hip_bfloat162 t = __float22bfloat162_rn(make_float2(a, b));
    union { __hip_bfloat162 h; unsigned u; } c; c.h = t; return c.u;
}

// async 16B global->LDS DMA (no VGPR round-trip; tracked by vmcnt)
__device__ __forceinline__ void mgn_cp16(const unsigned short* g, unsigned short* l) {
    __builtin_amdgcn_global_load_lds(
        (const __attribute__((address_space(1))) void*)g,
        (__attribute__((address_space(3))) void*)l, 16, 0, 0);
}
// Stage one 8 KB weight QUARTER (4096 shorts = 8 chunks of 512) with BW waves.
template <int BW>
__device__ __forceinline__ void mgn_stage_q(const unsigned short* __restrict__ src,
                                            unsigned short* wbuf, int tid) {
    const int w = tid >> 6, l = tid & 63;
#pragma unroll
    for (int i = 0; i < 8 / BW; ++i) {
        const int off = (w * (8 / BW) + i) * 512 + l * 8;   // shorts
        mgn_cp16(src + off, wbuf + off);
    }
}

// One weight-quarter of MFMAs: 4 t-groups x 2 sp, both row-tiles.
// TQ = accumulator offset (0 or 4); a0p/a1p point at the K-half's A-frag pair.
template <int TQ>
__device__ __forceinline__ void mgn_qcomp(const unsigned short* __restrict__ buf, int l,
                                          const mgn_sh8* a0p, const mgn_sh8* a1p,
                                          mgn_f32x4* acc0, mgn_f32x4* acc1) {
#pragma unroll
    for (int t = 0; t < 4; ++t)
#pragma unroll
        for (int sp = 0; sp < 2; ++sp) {
            mgn_sh8 b = *(const mgn_sh8*)&buf[(t * 2 + sp) * 512 + l * 8];
            acc0[TQ + t] = __builtin_amdgcn_mfma_f32_16x16x32_bf16(a0p[sp], b, acc0[TQ + t], 0, 0, 0);
            acc1[TQ + t] = __builtin_amdgcn_mfma_f32_16x16x32_bf16(a1p[sp], b, acc1[TQ + t], 0, 0, 0);
        }
}

// ---------------------------------------------------------------------------
// flag = 1 -> ij is int32, flag = 0 -> ij is int64
__global__ void mgn_detect_kernel(const int* __restrict__ ij, int* __restrict__ flag) {
    __shared__ int any;
    if (threadIdx.x == 0) any = 0;
    __syncthreads();
    if (ij[2 * threadIdx.x + 1] != 0) atomicOr(&any, 1);
    __syncthreads();
    if (threadIdx.x == 0) *flag = any;
}

__device__ __forceinline__ long mgn_load_idx(const int* __restrict__ ij, long pos, int is32) {
    if (is32) return (long)ij[pos];
    const long long* ij8 = (const long long*)ij;
    return (long)ij8[pos];
}

// ---------------------------------------------------------------------------
// Pack fp32 row-major W[d][k][n] into half-major MFMA B-frag order:
// i = ((((d*2+sh)*8+t)*2+sp)*64+lane)*8+j holds
//   W[d][(sh*2+sp)*32 + (lane>>4)*8 + j][(lane&15)*8 + t]
// so K-half sh is a contiguous 16 KB block (two contiguous 8 KB quarters:
// t0..3 then t4..7); lane owns 8 consecutive out cols.
__global__ void mgn_pack_kernel(const float* __restrict__ W, unsigned short* __restrict__ pw) {
    int i = blockIdx.x * blockDim.x + threadIdx.x;
    if (i >= PWMAT) return;
    int j    = i & 7;
    int lane = (i >> 3) & 63;
    int sp   = (i >> 9) & 1;
    int t    = (i >> 10) & 7;
    int sh   = (i >> 13) & 1;
    int d    = i >> 14;
    int k = (sh * 2 + sp) * 32 + (lane >> 4) * 8 + j;
    int n = (lane & 15) * 8 + t;
    pw[i] = (unsigned short)mgn_bf16bits(W[(d * NDIMC + k) * NDIMC + n]);
}

// ---------------------------------------------------------------------------
// CSR build: histogram -> scan -> fill
__global__ void mgn_deg_kernel(const int* __restrict__ ij, const int* __restrict__ flag,
                               int* __restrict__ deg) {
    int e = blockIdx.x * blockDim.x + threadIdx.x;
    if (e >= NEDGES) return;
    int dst = (int)mgn_load_idx(ij, (long)NEDGES + e, *flag);
    atomicAdd(&deg[dst], 1);
}

__global__ void mgn_scan_kernel(const int* __restrict__ deg,
                                int* __restrict__ rowstart, int* __restrict__ cursor) {
    __shared__ int partial[256];
    const int tid = threadIdx.x;
    const int CH = (NNODES + 255) / 256;   // 196
    const int base = tid * CH;
    int s = 0;
    for (int i = 0; i < CH; ++i) {
        int idx = base + i;
        if (idx < NNODES) s += deg[idx];
    }
    partial[tid] = s;
    __syncthreads();
    for (int off = 1; off < 256; off <<= 1) {
        int add = (tid >= off) ? partial[tid - off] : 0;
        __syncthreads();
        partial[tid] += add;
        __syncthreads();
    }
    int run = (tid == 0) ? 0 : partial[tid - 1];
    for (int i = 0; i < CH; ++i) {
        int idx = base + i;
        if (idx < NNODES) {
            rowstart[idx] = run;
            cursor[idx]   = run;
            run += deg[idx];
        }
    }
    if (tid == 255) rowstart[NNODES] = run;
}

__global__ void mgn_fill_kernel(const int* __restrict__ ij, const int* __restrict__ flag,
                                int* __restrict__ cursor, int* __restrict__ eidx) {
    int e = blockIdx.x * blockDim.x + threadIdx.x;
    if (e >= NEDGES) return;
    int dst = (int)mgn_load_idx(ij, (long)NEDGES + e, *flag);
    int pos = atomicAdd(&cursor[dst], 1);
    eidx[pos] = e;
}

// ---------------------------------------------------------------------------
__global__ void mgn_encoder_kernel(const float* __restrict__ v,
                                   const float* __restrict__ encW,
                                   const float* __restrict__ encB,
                                   float* __restrict__ h) {
    int idx = blockIdx.x * blockDim.x + threadIdx.x;
    if (idx >= NNODES * NDIMC) return;
    int n = idx >> 7, d = idx & 127;
    float acc = encB[d];
#pragma unroll
    for (int k = 0; k < NODEIN; ++k)
        acc = fmaf(v[n * NODEIN + k], encW[k * NDIMC + d], acc);
    h[idx] = acc;
}

__global__ void mgn_decoder_kernel(const float* __restrict__ h,
                                   const float* __restrict__ decW,
                                   const float* __restrict__ decB,
                                   float* __restrict__ out) {
    int idx = blockIdx.x * blockDim.x + threadIdx.x;
    if (idx >= NNODES * NODEIN) return;
    int n = idx / NODEIN, j = idx % NODEIN;
    float acc = decB[j];
#pragma unroll 8
    for (int k = 0; k < NDIMC; ++k)
        acc = fmaf(h[n * NDIMC + k], decW[k * NODEIN + j], acc);
    out[idx] = acc;
}

// ---------------------------------------------------------------------------
// Fused 6-deep residual MLP, bf16 MFMA core, fp32 residual/LN.
// r19: M=32/wave AND 3 blocks/CU. Session evidence:
//   r0 (M=16, 16KB ping-pong, 3 blk): 1660 cyc/row, 1.81 rows/kcyc/CU
//   r17 (M=32, 2 blk): 1180 cyc/row (-29%!) but occupancy loss net-regressed
//   r18 (weights from L2): 19.2 GB L2 B-traffic/dispatch serializes — weights
//       MUST come from LDS (per-CU replication is the only adequate BW).
// Fix: weight ping-pong at 8 KB QUARTER granularity (2x8KB buffers instead of
// 2x16KB). LDS = 34816 (xl) + 16384 (wq) = 51.2 KB -> 3 blocks/CU with M=32.
// 8 phases/depth (8 barriers), each: stage next quarter | 8 MFMAs x 2 row-
// tiles from current quarter. Barriers/row unchanged vs r0; B-LDS-reads/row
// halved vs r0. Quarter q of a K-half = t-groups {0..3} or {4..7} (contiguous
// 8 KB in packed layout). Per-phase CU LDS-read time (~1.1k cyc) hides the
// ~300 cyc L2 staging latency.
// e lives in CSR-slot order; node aggregation reads Eb[rs..re] contiguously.
// LN single-pass (sum/sumsq, folded coefficients).
template <int MODE, int BW>
__global__ __launch_bounds__(BW * 64, 3) void mgn_mlp6_mfma_kernel(
    float* __restrict__ Xf,               // node: h
    unsigned short* __restrict__ Eb,      // e buffer (CSR-slot order)
    const float* __restrict__ H,          // edge: h for gather
    const int* __restrict__ ij,
    const int* __restrict__ flag,
    const int* __restrict__ rowstart,     // node CSR
    const int* __restrict__ eidx,         // edge: slot -> original edge id
    int addE, int nrows,
    const unsigned short* __restrict__ PW1,
    const unsigned short* __restrict__ PW2,
    const float* __restrict__ B1, const float* __restrict__ B2,
    const float* __restrict__ G,  const float* __restrict__ BT)
{
    __shared__ unsigned short xl[BW * 32 * 136];   // x/h1 tile, row stride 136 (34816 B)
    __shared__ unsigned short wqA[4096];           // weight quarter ping (8 KB)
    __shared__ unsigned short wqB[4096];           // weight quarter pong (8 KB)
    const int tid = threadIdx.x;
    const int w   = tid >> 6;
    const int l   = tid & 63;
    const int q   = l >> 4;
    const int lm  = l & 15;
    const int ct  = lm * 8;                        // first of lane's 8 cols
    const int wbase = w * 32;                      // wave's first local row
    const long rowbase = (long)blockIdx.x * (32 * BW);

    const int is32 = (MODE == 1) ? *flag : 0;

    // pre-stage Q0 of depth 0 (W1 h0 t0..3) -> wqA; drains at first barrier
    mgn_stage_q<BW>(PW1, wqA, tid);

    // ---- tile load: xres fp32 regs (C layout) + LDS bf16 (A source)
    // lane owns 8 rows: row-tile u = rr>>2, r = rr&3
    float xres[8][8];
#pragma unroll
    for (int rr = 0; rr < 8; ++rr) {
        const int rloc = wbase + (rr >> 2) * 16 + q * 4 + (rr & 3);
        long gr = rowbase + rloc;
        bool ok = gr < nrows;
        float xv[8];
#pragma unroll
        for (int t = 0; t < 8; ++t) xv[t] = 0.f;
        if (MODE == 1) {
            if (ok) {
                long er = (long)eidx[gr];     // original edge id for this slot
                long i0 = mgn_load_idx(ij, er, is32);
                long i1 = mgn_load_idx(ij, (long)NEDGES + er, is32);
                const float* p0 = H + i0 * NDIMC + ct;
                const float* p1 = H + i1 * NDIMC + ct;
                float4 a0 = *(const float4*)p0, a1 = *(const float4*)(p0 + 4);
                float4 b0 = *(const float4*)p1, b1 = *(const float4*)(p1 + 4);
                xv[0] = a0.x - b0.x; xv[1] = a0.y - b0.y;
                xv[2] = a0.z - b0.z; xv[3] = a0.w - b0.w;
                xv[4] = a1.x - b1.x; xv[5] = a1.y - b1.y;
                xv[6] = a1.z - b1.z; xv[7] = a1.w - b1.w;
                if (addE) {
                    uint4 u4 = *(const uint4*)(Eb + (size_t)gr * NDIMC + ct);
                    xv[0] += __uint_as_float(u4.x << 16);
                    xv[1] += __uint_as_float(u4.x & 0xffff0000u);
                    xv[2] += __uint_as_float(u4.y << 16);
                    xv[3] += __uint_as_float(u4.y & 0xffff0000u);
                    xv[4] += __uint_as_float(u4.z << 16);
                    xv[5] += __uint_as_float(u4.z & 0xffff0000u);
                    xv[6] += __uint_as_float(u4.w << 16);
                    xv[7] += __uint_as_float(u4.w & 0xffff0000u);
                }
            }
        } else {
            if (ok) {
                float4 a0 = *(const float4*)(Xf + gr * NDIMC + ct);
                float4 a1 = *(const float4*)(Xf + gr * NDIMC + ct + 4);
                xv[0] = a0.x; xv[1] = a0.y; xv[2] = a0.z; xv[3] = a0.w;
                xv[4] = a1.x; xv[5] = a1.y; xv[6] = a1.z; xv[7] = a1.w;
                // CSR aggregate: CONTIGUOUS slot range (no indirection)
                int rs = rowstart[gr], re = rowstart[gr + 1];
                for (int k = rs; k < re; ++k) {
                    uint4 u4 = *(const uint4*)(Eb + (size_t)k * NDIMC + ct);
                    xv[0] += __uint_as_float(u4.x << 16);
                    xv[1] += __uint_as_float(u4.x & 0xffff0000u);
                    xv[2] += __uint_as_float(u4.y << 16);
                    xv[3] += __uint_as_float(u4.y & 0xffff0000u);
                    xv[4] += __uint_as_float(u4.z << 16);
                    xv[5] += __uint_as_float(u4.z & 0xffff0000u);
                    xv[6] += __uint_as_float(u4.w << 16);
                    xv[7] += __uint_as_float(u4.w & 0xffff0000u);
                }
            }
        }
#pragma unroll
        for (int t = 0; t < 8; ++t) xres[rr][t] = xv[t];
        uint4 pk;
        pk.x = mgn_pk(xv[0], xv[1]); pk.y = mgn_pk(xv[2], xv[3]);
        pk.z = mgn_pk(xv[4], xv[5]); pk.w = mgn_pk(xv[6], xv[7]);
        *(uint4*)&xl[rloc * 136 + ct] = pk;
    }

    __syncthreads();   // Q0 visible in wqA

    mgn_sh8 a0[4], a1[4];          // A frags for the two row-tiles
    mgn_f32x4 acc0[8], acc1[8];
    const int arow0 = (wbase + lm) * 136;
    const int arow1 = (wbase + 16 + lm) * 136;

    for (int d = 0; d < DEPTHC; ++d) {
        const unsigned short* pw1 = PW1 + (size_t)d * 16384;
        const unsigned short* pw2 = PW2 + (size_t)d * 16384;

        float4 b1a = *(const float4*)(B1 + d * NDIMC + ct);
        float4 b1b = *(const float4*)(B1 + d * NDIMC + ct + 4);
        float b1v[8] = {b1a.x, b1a.y, b1a.z, b1a.w, b1b.x, b1b.y, b1b.z, b1b.w};

        // A-frags for GEMM1 (x); acc preloaded with b1
#pragma unroll
        for (int s = 0; s < 4; ++s) {
            a0[s] = *(const mgn_sh8*)&xl[arow0 + s * 32 + q * 8];
            a1[s] = *(const mgn_sh8*)&xl[arow1 + s * 32 + q * 8];
        }
#pragma unroll
        for (int t = 0; t < 8; ++t) {
            acc0[t] = (mgn_f32x4){b1v[t], b1v[t], b1v[t], b1v[t]};
            acc1[t] = acc0[t];
        }

        // ---- ph0: stage Q1->B | Q0 = GEMM1 h0 t0..3 (A)
        mgn_stage_q<BW>(pw1 + 4096, wqB, tid);
        mgn_qcomp<0>(wqA, l, a0 + 0, a1 + 0, acc0, acc1);
        __syncthreads();
        // ---- ph1: stage Q2->A | Q1 = GEMM1 h0 t4..7 (B)
        mgn_stage_q<BW>(pw1 + 8192, wqA, tid);
        mgn_qcomp<4>(wqB, l, a0 + 0, a1 + 0, acc0, acc1);
        __syncthreads();
        // ---- ph2: stage Q3->B | Q2 = GEMM1 h1 t0..3 (A)
        mgn_stage_q<BW>(pw1 + 12288, wqB, tid);
        mgn_qcomp<0>(wqA, l, a0 + 2, a1 + 2, acc0, acc1);
        __syncthreads();
        // ---- ph3: stage Q4->A | Q3 = GEMM1 h1 t4..7 (B) + h1 epilogue
        mgn_stage_q<BW>(pw2, wqA, tid);
        mgn_qcomp<4>(wqB, l, a0 + 2, a1 + 2, acc0, acc1);
#pragma unroll
        for (int rr = 0; rr < 8; ++rr) {
            const int rloc = wbase + (rr >> 2) * 16 + q * 4 + (rr & 3);
            const int r = rr & 3;
            float h1[8];
#pragma unroll
            for (int t = 0; t < 8; ++t)
                h1[t] = fmaxf((rr < 4) ? acc0[t][r] : acc1[t][r], 0.f);
            uint4 pk;
            pk.x = mgn_pk(h1[0], h1[1]); pk.y = mgn_pk(h1[2], h1[3]);
            pk.z = mgn_pk(h1[4], h1[5]); pk.w = mgn_pk(h1[6], h1[7]);
            *(uint4*)&xl[rloc * 136 + ct] = pk;
        }
        __syncthreads();

        float4 b2a = *(const float4*)(B2 + d * NDIMC + ct);
        float4 b2b = *(const float4*)(B2 + d * NDIMC + ct + 4);
        float4 ga  = *(const float4*)(G  + d * NDIMC + ct);
        float4 gb  = *(const float4*)(G  + d * NDIMC + ct + 4);
        float4 bta = *(const float4*)(BT + d * NDIMC + ct);
        float4 btb = *(const float4*)(BT + d * NDIMC + ct + 4);
        float b2v[8] = {b2a.x, b2a.y, b2a.z, b2a.w, b2b.x, b2b.y, b2b.z, b2b.w};
        float gv[8]  = {ga.x, ga.y, ga.z, ga.w, gb.x, gb.y, gb.z, gb.w};
        float btv[8] = {bta.x, bta.y, bta.z, bta.w, btb.x, btb.y, btb.z, btb.w};

        // A-frags for GEMM2 (h1); acc re-init with b2
#pragma unroll
        for (int s = 0; s < 4; ++s) {
            a0[s] = *(const mgn_sh8*)&xl[arow0 + s * 32 + q * 8];
            a1[s] = *(const mgn_sh8*)&xl[arow1 + s * 32 + q * 8];
        }
#pragma unroll
        for (int t = 0; t < 8; ++t) {
            acc0[t] = (mgn_f32x4){b2v[t], b2v[t], b2v[t], b2v[t]};
            acc1[t] = acc0[t];
        }

        // ---- ph4: stage Q5->B | Q4 = GEMM2 h0 t0..3 (A)
        mgn_stage_q<BW>(pw2 + 4096, wqB, tid);
        mgn_qcomp<0>(wqA, l, a0 + 0, a1 + 0, acc0, acc1);
        __syncthreads();
        // ---- ph5: stage Q6->A | Q5 = GEMM2 h0 t4..7 (B)
        mgn_stage_q<BW>(pw2 + 8192, wqA, tid);
        mgn_qcomp<4>(wqB, l, a0 + 0, a1 + 0, acc0, acc1);
        __syncthreads();
        // ---- ph6: stage Q7->B | Q6 = GEMM2 h1 t0..3 (A)
        mgn_stage_q<BW>(pw2 + 12288, wqB, tid);
        mgn_qcomp<0>(wqA, l, a0 + 2, a1 + 2, acc0, acc1);
        __syncthreads();
        // ---- ph7: stage next-depth Q0->A | Q7 = GEMM2 h1 t4..7 (B) + LN epi
        if (d + 1 < DEPTHC)
            mgn_stage_q<BW>(PW1 + (size_t)(d + 1) * 16384, wqA, tid);
        mgn_qcomp<4>(wqB, l, a0 + 2, a1 + 2, acc0, acc1);
#pragma unroll
        for (int rr = 0; rr < 8; ++rr) {
            const int rloc = wbase + (rr >> 2) * 16 + q * 4 + (rr & 3);
            const int r = rr & 3;
            float h2[8];
#pragma unroll
            for (int t = 0; t < 8; ++t)
                h2[t] = fmaxf((rr < 4) ? acc0[t][r] : acc1[t][r], 0.f);
            // single-pass sum & sumsq; independent shfl chains overlap
            float sum = 0.f, ssq = 0.f;
#pragma unroll
            for (int t = 0; t < 8; ++t) {
                sum += h2[t];
                ssq = fmaf(h2[t], h2[t], ssq);
            }
            sum += __shfl_xor(sum, 1); ssq += __shfl_xor(ssq, 1);
            sum += __shfl_xor(sum, 2); ssq += __shfl_xor(ssq, 2);
            sum += __shfl_xor(sum, 4); ssq += __shfl_xor(ssq, 4);
            sum += __shfl_xor(sum, 8); ssq += __shfl_xor(ssq, 8);
            float mean = sum * 0.0078125f;
            float var  = fmaf(-mean, mean, ssq * 0.0078125f);
            float rstd = rsqrtf(var + LNEPS);
#pragma unroll
            for (int t = 0; t < 8; ++t) {
                float at = rstd * gv[t];
                float ctt = fmaf(-mean, at, btv[t]);
                xres[rr][t] += fmaf(h2[t], at, ctt);
            }
            if (d != DEPTHC - 1) {
                uint4 pk;
                pk.x = mgn_pk(xres[rr][0], xres[rr][1]);
                pk.y = mgn_pk(xres[rr][2], xres[rr][3]);
                pk.z = mgn_pk(xres[rr][4], xres[rr][5]);
                pk.w = mgn_pk(xres[rr][6], xres[rr][7]);
                *(uint4*)&xl[rloc * 136 + ct] = pk;
            }
        }
        if (d + 1 < DEPTHC) __syncthreads();   // next-depth Q0 visible in wqA
    }

    // ---- tile store
#pragma unroll
    for (int rr = 0; rr < 8; ++rr) {
        const int rloc = wbase + (rr >> 2) * 16 + q * 4 + (rr & 3);
        long gr = rowbase + rloc;
        if (gr < nrows) {
            if (MODE == 1) {
                uint4 pk;
                pk.x = mgn_pk(xres[rr][0], xres[rr][1]);
                pk.y = mgn_pk(xres[rr][2], xres[rr][3]);
                pk.z = mgn_pk(xres[rr][4], xres[rr][5]);
                pk.w = mgn_pk(xres[rr][6], xres[rr][7]);
                *(uint4*)(Eb + (size_t)gr * NDIMC + ct) = pk;
            } else {
                float4 o0 = {xres[rr][0], xres[rr][1], xres[rr][2], xres[rr][3]};
                float4 o1 = {xres[rr][4], xres[rr][5], xres[rr][6], xres[rr][7]};
                *(float4*)(Xf + gr * NDIMC + ct)     = o0;
                *(float4*)(Xf + gr * NDIMC + ct + 4) = o1;
            }
        }
    }
}

// ---------------------------------------------------------------------------
extern "C" void kernel_launch(void* const* d_in, const int* in_sizes, int n_in,
                              void* d_out, int out_size, void* d_ws, size_t ws_size,
                              hipStream_t stream) {
    const float* v    = (const float*)d_in[0];
    const int*   ij   = (const int*)d_in[1];
    const float* encW = (const float*)d_in[2];
    const float* encB = (const float*)d_in[3];
    const float* eW1  = (const float*)d_in[4];
    const float* eB1  = (const float*)d_in[5];
    const float* eW2  = (const float*)d_in[6];
    const float* eB2  = (const float*)d_in[7];
    const float* eG   = (const float*)d_in[8];
    const float* eBT  = (const float*)d_in[9];
    const float* nW1  = (const float*)d_in[10];
    const float* nB1  = (const float*)d_in[11];
    const float* nW2  = (const float*)d_in[12];
    const float* nB2  = (const float*)d_in[13];
    const float* nG   = (const float*)d_in[14];
    const float* nBT  = (const float*)d_in[15];
    const float* decW = (const float*)d_in[16];
    const float* decB = (const float*)d_in[17];
    float* out = (float*)d_out;

    char* ws = (char*)d_ws;
    float*          h    = (float*)(ws + H_OFF);
    unsigned short* ebuf = (unsigned short*)(ws + E_OFF);
    unsigned short* pw   = (unsigned short*)(ws + PW_OFF);
    int*            flag = (int*)(ws + FLAG_OFF);
    int*            deg  = (int*)(ws + DEG_OFF);
    int*            rstt = (int*)(ws + RS_OFF);
    int*            curs = (int*)(ws + CUR_OFF);
    int*            eidx = (int*)(ws + EIDX_OFF);

    mgn_detect_kernel<<<1, 256, 0, stream>>>(ij, flag);
    mgn_pack_kernel<<<(PWMAT + 255) / 256, 256, 0, stream>>>(eW1, pw + 0 * PWMAT);
    mgn_pack_kernel<<<(PWMAT + 255) / 256, 256, 0, stream>>>(eW2, pw + 1 * PWMAT);
    mgn_pack_kernel<<<(PWMAT + 255) / 256, 256, 0, stream>>>(nW1, pw + 2 * PWMAT);
    mgn_pack_kernel<<<(PWMAT + 255) / 256, 256, 0, stream>>>(nW2, pw + 3 * PWMAT);

    // CSR build (static graph; rebuilt every call for graph-capture safety)
    hipMemsetAsync(deg, 0, (size_t)(NNODES + 1) * sizeof(int), stream);
    mgn_deg_kernel<<<(NEDGES + 255) / 256, 256, 0, stream>>>(ij, flag, deg);
    mgn_scan_kernel<<<1, 256, 0, stream>>>(deg, rstt, curs);
    mgn_fill_kernel<<<(NEDGES + 255) / 256, 256, 0, stream>>>(ij, flag, curs, eidx);

    mgn_encoder_kernel<<<(NNODES * NDIMC + 255) / 256, 256, 0, stream>>>(v, encW, encB, h);

    for (int p = 0; p < NPASSESC; ++p) {
        // edge MLP (fused gather; e in CSR-slot order; 128 rows/block)
        mgn_mlp6_mfma_kernel<1, 4><<<NEDGES / 128, 256, 0, stream>>>(
            nullptr, ebuf, h, ij, flag, nullptr, eidx, p > 0 ? 1 : 0, NEDGES,
            pw + 0 * PWMAT, pw + 1 * PWMAT, eB1, eB2, eG, eBT);
        // node MLP with fused CSR aggregation (contiguous Eb reads; 128 rows/block)
        mgn_mlp6_mfma_kernel<0, 4><<<(NNODES + 127) / 128, 256, 0, stream>>>(
            h, ebuf, nullptr, nullptr, nullptr, rstt, nullptr, 0, NNODES,
            pw + 2 * PWMAT, pw + 3 * PWMAT, nB1, nB2, nG, nBT);
    }

    mgn_decoder_kernel<<<(NNODES * NODEIN + 255) / 256, 256, 0, stream>>>(h, decW, decB, out);
}

// Round 4
// 3200.117 us; speedup vs baseline: 1.4183x; 1.4183x over previous
//
#include <hip/hip_runtime.h>
#include <hip/hip_bf16.h>
#include <cstdint>
#include <cstddef>

#define NDIMC   128
#define DEPTHC  6
#define NPASSESC 4
#define NNODES  50000
#define NEDGES  800000
#define NODEIN  5
#define LNEPS   1e-5f

// ---------------------------------------------------------------------------
// ws layout (bytes) — ~224 MiB, below proven-safe 256,000,004
#define H_OFF    0ull                     // h:  50000*128*4  = 25.6 MB fp32
#define E_OFF    25600000ull              // e:  800000*128*2 = 204.8 MB bf16 (CSR-slot order)
#define PW_OFF   230400000ull             // packed weights: 4 * 196,608 B bf16
#define FLAG_OFF 231186432ull
#define DEG_OFF  231186436ull             // 50001 int
#define RS_OFF   231386440ull             // rowstart: 50001 int
#define CUR_OFF  231586444ull             // cursor:   50000 int
#define EIDX_OFF 231786444ull             // eidx:     800000 int -> ends 234,986,444
#define PWMAT    98304                    // shorts per packed matrix (6*4*4096)

typedef __attribute__((ext_vector_type(8))) short mgn_sh8;
typedef __attribute__((ext_vector_type(4))) float mgn_f32x4;

// ---------------------------------------------------------------------------
__device__ __forceinline__ unsigned mgn_bf16bits(float f) {
    unsigned x = __float_as_uint(f);
    return (x + 0x7fffu + ((x >> 16) & 1u)) >> 16;   // RNE
}
__device__ __forceinline__ unsigned mgn_pk(float a, float b) {
    __hip_bfloat162 t = __float22bfloat162_rn(make_float2(a, b));
    union { __hip_bfloat162 h; unsigned u; } c; c.h = t; return c.u;
}

// async 16B global->LDS DMA (no VGPR round-trip; tracked by vmcnt)
__device__ __forceinline__ void mgn_cp16(const unsigned short* g, unsigned short* l) {
    __builtin_amdgcn_global_load_lds(
        (const __attribute__((address_space(1))) void*)g,
        (__attribute__((address_space(3))) void*)l, 16, 0, 0);
}
// Stage one 8 KB weight QUARTER (4096 shorts = 8 chunks of 512) with BW waves.
template <int BW>
__device__ __forceinline__ void mgn_stage_q(const unsigned short* __restrict__ src,
                                            unsigned short* wbuf, int tid) {
    const int w = tid >> 6, l = tid & 63;
#pragma unroll
    for (int i = 0; i < 8 / BW; ++i) {
        const int off = (w * (8 / BW) + i) * 512 + l * 8;   // shorts
        mgn_cp16(src + off, wbuf + off);
    }
}

// One weight-quarter of MFMAs: 4 t'-groups x 2 sp, both row-tiles, ONE N-half.
// a0p/a1p point at the K-half's A-frag pair. acc = 4 per row-tile (N-half).
__device__ __forceinline__ void mgn_qcompN(const unsigned short* __restrict__ buf, int l,
                                           const mgn_sh8* a0p, const mgn_sh8* a1p,
                                           mgn_f32x4* acc0, mgn_f32x4* acc1) {
#pragma unroll
    for (int t = 0; t < 4; ++t)
#pragma unroll
        for (int sp = 0; sp < 2; ++sp) {
            mgn_sh8 b = *(const mgn_sh8*)&buf[(t * 2 + sp) * 512 + l * 8];
            acc0[t] = __builtin_amdgcn_mfma_f32_16x16x32_bf16(a0p[sp], b, acc0[t], 0, 0, 0);
            acc1[t] = __builtin_amdgcn_mfma_f32_16x16x32_bf16(a1p[sp], b, acc1[t], 0, 0, 0);
        }
}

// ---------------------------------------------------------------------------
// flag = 1 -> ij is int32, flag = 0 -> ij is int64
__global__ void mgn_detect_kernel(const int* __restrict__ ij, int* __restrict__ flag) {
    __shared__ int any;
    if (threadIdx.x == 0) any = 0;
    __syncthreads();
    if (ij[2 * threadIdx.x + 1] != 0) atomicOr(&any, 1);
    __syncthreads();
    if (threadIdx.x == 0) *flag = any;
}

__device__ __forceinline__ long mgn_load_idx(const int* __restrict__ ij, long pos, int is32) {
    if (is32) return (long)ij[pos];
    const long long* ij8 = (const long long*)ij;
    return (long)ij8[pos];
}

// ---------------------------------------------------------------------------
// Pack fp32 row-major W[d][k][n] into QUARTER-streamed MFMA B-frag order.
// Quarter qd = nh*2 + sh  (nh = N-half, sh = K-half) is a contiguous 8 KB
// block, in the exact order the N-split schedule consumes them:
//   qd0=(nh0,h0) qd1=(nh0,h1) qd2=(nh1,h0) qd3=(nh1,h1)
// i = ((((d*4+qd)*4+t')*2+sp)*64+lane)*8+j holds
//   W[d][(sh*2+sp)*32 + (lane>>4)*8 + j][(lane&15)*8 + nh*4 + t']
__global__ void mgn_pack_kernel(const float* __restrict__ W, unsigned short* __restrict__ pw) {
    int i = blockIdx.x * blockDim.x + threadIdx.x;
    if (i >= PWMAT) return;
    int j    = i & 7;
    int lane = (i >> 3) & 63;
    int sp   = (i >> 9) & 1;
    int tp   = (i >> 10) & 3;
    int qd   = (i >> 12) & 3;
    int d    = i >> 14;
    int sh = qd & 1, nh = qd >> 1;
    int k = (sh * 2 + sp) * 32 + (lane >> 4) * 8 + j;
    int n = (lane & 15) * 8 + nh * 4 + tp;
    pw[i] = (unsigned short)mgn_bf16bits(W[(d * NDIMC + k) * NDIMC + n]);
}

// ---------------------------------------------------------------------------
// CSR build: histogram -> scan -> fill
__global__ void mgn_deg_kernel(const int* __restrict__ ij, const int* __restrict__ flag,
                               int* __restrict__ deg) {
    int e = blockIdx.x * blockDim.x + threadIdx.x;
    if (e >= NEDGES) return;
    int dst = (int)mgn_load_idx(ij, (long)NEDGES + e, *flag);
    atomicAdd(&deg[dst], 1);
}

__global__ void mgn_scan_kernel(const int* __restrict__ deg,
                                int* __restrict__ rowstart, int* __restrict__ cursor) {
    __shared__ int partial[256];
    const int tid = threadIdx.x;
    const int CH = (NNODES + 255) / 256;   // 196
    const int base = tid * CH;
    int s = 0;
    for (int i = 0; i < CH; ++i) {
        int idx = base + i;
        if (idx < NNODES) s += deg[idx];
    }
    partial[tid] = s;
    __syncthreads();
    for (int off = 1; off < 256; off <<= 1) {
        int add = (tid >= off) ? partial[tid - off] : 0;
        __syncthreads();
        partial[tid] += add;
        __syncthreads();
    }
    int run = (tid == 0) ? 0 : partial[tid - 1];
    for (int i = 0; i < CH; ++i) {
        int idx = base + i;
        if (idx < NNODES) {
            rowstart[idx] = run;
            cursor[idx]   = run;
            run += deg[idx];
        }
    }
    if (tid == 255) rowstart[NNODES] = run;
}

__global__ void mgn_fill_kernel(const int* __restrict__ ij, const int* __restrict__ flag,
                                int* __restrict__ cursor, int* __restrict__ eidx) {
    int e = blockIdx.x * blockDim.x + threadIdx.x;
    if (e >= NEDGES) return;
    int dst = (int)mgn_load_idx(ij, (long)NEDGES + e, *flag);
    int pos = atomicAdd(&cursor[dst], 1);
    eidx[pos] = e;
}

// ---------------------------------------------------------------------------
__global__ void mgn_encoder_kernel(const float* __restrict__ v,
                                   const float* __restrict__ encW,
                                   const float* __restrict__ encB,
                                   float* __restrict__ h) {
    int idx = blockIdx.x * blockDim.x + threadIdx.x;
    if (idx >= NNODES * NDIMC) return;
    int n = idx >> 7, d = idx & 127;
    float acc = encB[d];
#pragma unroll
    for (int k = 0; k < NODEIN; ++k)
        acc = fmaf(v[n * NODEIN + k], encW[k * NDIMC + d], acc);
    h[idx] = acc;
}

__global__ void mgn_decoder_kernel(const float* __restrict__ h,
                                   const float* __restrict__ decW,
                                   const float* __restrict__ decB,
                                   float* __restrict__ out) {
    int idx = blockIdx.x * blockDim.x + threadIdx.x;
    if (idx >= NNODES * NODEIN) return;
    int n = idx / NODEIN, j = idx % NODEIN;
    float acc = decB[j];
#pragma unroll 8
    for (int k = 0; k < NDIMC; ++k)
        acc = fmaf(h[n * NDIMC + k], decW[k * NODEIN + j], acc);
    out[idx] = acc;
}

// ---------------------------------------------------------------------------
// Fused 6-deep residual MLP, bf16 MFMA core, fp32 residual/LN.
// r20: M=32/wave, 3 blocks/CU, N-SPLIT GEMMs. r19 post-mortem: schedule was
// right but regs didn't fit the 3-waves/SIMD cap (~170): acc 64 + xres 64 +
// a 32 + temps > cap -> xres spilled -> 1.37 GB scratch writes/dispatch.
// Fix: process output columns in two N-halves -> live acc = 32 (acc0[4]+
// acc1[4]); weight pack reordered so quarters stream in (nh, sh) order.
// B-elements still read from LDS exactly once per wave (M=32 reuse).
// Live set: xres 64 + a 32 + acc 32 + temps ~25 = ~155 <= 170. No spills.
// h2's first N-half is stashed bf16 in xl (free after A2-frag load) for the
// LN pass; one extra bf16 rounding on half the LN input (same order as the
// bf16 rounding already throughout).
// LDS = 34816 (xl) + 2*8192 (wq ping-pong) = 51.2 KB -> 3 blocks/CU.
// 8 phases/depth, each: stage next 8 KB quarter | 16 MFMAs from current.
// e lives in CSR-slot order; node aggregation reads Eb[rs..re] contiguously.
template <int MODE, int BW>
__global__ __launch_bounds__(BW * 64, 3) void mgn_mlp6_mfma_kernel(
    float* __restrict__ Xf,               // node: h
    unsigned short* __restrict__ Eb,      // e buffer (CSR-slot order)
    const float* __restrict__ H,          // edge: h for gather
    const int* __restrict__ ij,
    const int* __restrict__ flag,
    const int* __restrict__ rowstart,     // node CSR
    const int* __restrict__ eidx,         // edge: slot -> original edge id
    int addE, int nrows,
    const unsigned short* __restrict__ PW1,
    const unsigned short* __restrict__ PW2,
    const float* __restrict__ B1, const float* __restrict__ B2,
    const float* __restrict__ G,  const float* __restrict__ BT)
{
    __shared__ unsigned short xl[BW * 32 * 136];   // x/h1 tile, row stride 136 (34816 B)
    __shared__ unsigned short wqA[4096];           // weight quarter ping (8 KB)
    __shared__ unsigned short wqB[4096];           // weight quarter pong (8 KB)
    const int tid = threadIdx.x;
    const int w   = tid >> 6;
    const int l   = tid & 63;
    const int q   = l >> 4;
    const int lm  = l & 15;
    const int ct  = lm * 8;                        // first of lane's 8 cols
    const int wbase = w * 32;                      // wave's first local row
    const long rowbase = (long)blockIdx.x * (32 * BW);

    const int is32 = (MODE == 1) ? *flag : 0;

    // pre-stage depth-0 W1 quarter 0 -> wqA; drains at first barrier
    mgn_stage_q<BW>(PW1, wqA, tid);

    // ---- tile load: xres fp32 regs (C layout) + LDS bf16 (A source)
    // lane owns 8 rows: row-tile u = rr>>2, r = rr&3
    float xres[8][8];
#pragma unroll
    for (int rr = 0; rr < 8; ++rr) {
        const int rloc = wbase + (rr >> 2) * 16 + q * 4 + (rr & 3);
        long gr = rowbase + rloc;
        bool ok = gr < nrows;
        float xv[8];
#pragma unroll
        for (int t = 0; t < 8; ++t) xv[t] = 0.f;
        if (MODE == 1) {
            if (ok) {
                long er = (long)eidx[gr];     // original edge id for this slot
                long i0 = mgn_load_idx(ij, er, is32);
                long i1 = mgn_load_idx(ij, (long)NEDGES + er, is32);
                const float* p0 = H + i0 * NDIMC + ct;
                const float* p1 = H + i1 * NDIMC + ct;
                float4 a0 = *(const float4*)p0, a1 = *(const float4*)(p0 + 4);
                float4 b0 = *(const float4*)p1, b1 = *(const float4*)(p1 + 4);
                xv[0] = a0.x - b0.x; xv[1] = a0.y - b0.y;
                xv[2] = a0.z - b0.z; xv[3] = a0.w - b0.w;
                xv[4] = a1.x - b1.x; xv[5] = a1.y - b1.y;
                xv[6] = a1.z - b1.z; xv[7] = a1.w - b1.w;
                if (addE) {
                    uint4 u4 = *(const uint4*)(Eb + (size_t)gr * NDIMC + ct);
                    xv[0] += __uint_as_float(u4.x << 16);
                    xv[1] += __uint_as_float(u4.x & 0xffff0000u);
                    xv[2] += __uint_as_float(u4.y << 16);
                    xv[3] += __uint_as_float(u4.y & 0xffff0000u);
                    xv[4] += __uint_as_float(u4.z << 16);
                    xv[5] += __uint_as_float(u4.z & 0xffff0000u);
                    xv[6] += __uint_as_float(u4.w << 16);
                    xv[7] += __uint_as_float(u4.w & 0xffff0000u);
                }
            }
        } else {
            if (ok) {
                float4 a0 = *(const float4*)(Xf + gr * NDIMC + ct);
                float4 a1 = *(const float4*)(Xf + gr * NDIMC + ct + 4);
                xv[0] = a0.x; xv[1] = a0.y; xv[2] = a0.z; xv[3] = a0.w;
                xv[4] = a1.x; xv[5] = a1.y; xv[6] = a1.z; xv[7] = a1.w;
                // CSR aggregate: CONTIGUOUS slot range (no indirection)
                int rs = rowstart[gr], re = rowstart[gr + 1];
                for (int k = rs; k < re; ++k) {
                    uint4 u4 = *(const uint4*)(Eb + (size_t)k * NDIMC + ct);
                    xv[0] += __uint_as_float(u4.x << 16);
                    xv[1] += __uint_as_float(u4.x & 0xffff0000u);
                    xv[2] += __uint_as_float(u4.y << 16);
                    xv[3] += __uint_as_float(u4.y & 0xffff0000u);
                    xv[4] += __uint_as_float(u4.z << 16);
                    xv[5] += __uint_as_float(u4.z & 0xffff0000u);
                    xv[6] += __uint_as_float(u4.w << 16);
                    xv[7] += __uint_as_float(u4.w & 0xffff0000u);
                }
            }
        }
#pragma unroll
        for (int t = 0; t < 8; ++t) xres[rr][t] = xv[t];
        uint4 pk;
        pk.x = mgn_pk(xv[0], xv[1]); pk.y = mgn_pk(xv[2], xv[3]);
        pk.z = mgn_pk(xv[4], xv[5]); pk.w = mgn_pk(xv[6], xv[7]);
        *(uint4*)&xl[rloc * 136 + ct] = pk;
    }

    __syncthreads();   // depth-0 Q0 visible in wqA

    mgn_sh8 a0[4], a1[4];          // A frags for the two row-tiles (full K)
    mgn_f32x4 acc0[4], acc1[4];    // one N-half of accumulators
    const int arow0 = (wbase + lm) * 136;
    const int arow1 = (wbase + 16 + lm) * 136;

    for (int d = 0; d < DEPTHC; ++d) {
        const unsigned short* pw1 = PW1 + (size_t)d * 16384;
        const unsigned short* pw2 = PW2 + (size_t)d * 16384;

        // ---- A1 frags (x, full K) into regs
#pragma unroll
        for (int s = 0; s < 4; ++s) {
            a0[s] = *(const mgn_sh8*)&xl[arow0 + s * 32 + q * 8];
            a1[s] = *(const mgn_sh8*)&xl[arow1 + s * 32 + q * 8];
        }
        {   // acc init: b1 cols ct..ct+3 (N-half 0)
            float4 bb = *(const float4*)(B1 + d * NDIMC + ct);
            acc0[0] = (mgn_f32x4){bb.x, bb.x, bb.x, bb.x};
            acc0[1] = (mgn_f32x4){bb.y, bb.y, bb.y, bb.y};
            acc0[2] = (mgn_f32x4){bb.z, bb.z, bb.z, bb.z};
            acc0[3] = (mgn_f32x4){bb.w, bb.w, bb.w, bb.w};
            acc1[0] = acc0[0]; acc1[1] = acc0[1]; acc1[2] = acc0[2]; acc1[3] = acc0[3];
        }

        // ---- ph0: stage qd1->B | qd0 (nh0,h0) from A
        mgn_stage_q<BW>(pw1 + 4096, wqB, tid);
        mgn_qcompN(wqA, l, a0 + 0, a1 + 0, acc0, acc1);
        __syncthreads();
        // ---- ph1: stage qd2->A | qd1 (nh0,h1) from B; h1-nh0 stash; acc -> nh1
        mgn_stage_q<BW>(pw1 + 8192, wqA, tid);
        mgn_qcompN(wqB, l, a0 + 2, a1 + 2, acc0, acc1);
#pragma unroll
        for (int rr = 0; rr < 8; ++rr) {
            const int rloc = wbase + (rr >> 2) * 16 + q * 4 + (rr & 3);
            const int r = rr & 3;
            float v0 = fmaxf((rr < 4) ? acc0[0][r] : acc1[0][r], 0.f);
            float v1 = fmaxf((rr < 4) ? acc0[1][r] : acc1[1][r], 0.f);
            float v2 = fmaxf((rr < 4) ? acc0[2][r] : acc1[2][r], 0.f);
            float v3 = fmaxf((rr < 4) ? acc0[3][r] : acc1[3][r], 0.f);
            uint2 pk; pk.x = mgn_pk(v0, v1); pk.y = mgn_pk(v2, v3);
            *(uint2*)&xl[rloc * 136 + ct] = pk;
        }
        {   // acc init: b1 cols ct+4..ct+7 (N-half 1)
            float4 bb = *(const float4*)(B1 + d * NDIMC + ct + 4);
            acc0[0] = (mgn_f32x4){bb.x, bb.x, bb.x, bb.x};
            acc0[1] = (mgn_f32x4){bb.y, bb.y, bb.y, bb.y};
            acc0[2] = (mgn_f32x4){bb.z, bb.z, bb.z, bb.z};
            acc0[3] = (mgn_f32x4){bb.w, bb.w, bb.w, bb.w};
            acc1[0] = acc0[0]; acc1[1] = acc0[1]; acc1[2] = acc0[2]; acc1[3] = acc0[3];
        }
        __syncthreads();
        // ---- ph2: stage qd3->B | qd2 (nh1,h0) from A
        mgn_stage_q<BW>(pw1 + 12288, wqB, tid);
        mgn_qcompN(wqA, l, a0 + 0, a1 + 0, acc0, acc1);
        __syncthreads();
        // ---- ph3: stage W2 qd0->A | qd3 (nh1,h1) from B; h1-nh1 stash; A2 load; acc -> W2 nh0
        mgn_stage_q<BW>(pw2, wqA, tid);
        mgn_qcompN(wqB, l, a0 + 2, a1 + 2, acc0, acc1);
#pragma unroll
        for (int rr = 0; rr < 8; ++rr) {
            const int rloc = wbase + (rr >> 2) * 16 + q * 4 + (rr & 3);
            const int r = rr & 3;
            float v0 = fmaxf((rr < 4) ? acc0[0][r] : acc1[0][r], 0.f);
            float v1 = fmaxf((rr < 4) ? acc0[1][r] : acc1[1][r], 0.f);
            float v2 = fmaxf((rr < 4) ? acc0[2][r] : acc1[2][r], 0.f);
            float v3 = fmaxf((rr < 4) ? acc0[3][r] : acc1[3][r], 0.f);
            uint2 pk; pk.x = mgn_pk(v0, v1); pk.y = mgn_pk(v2, v3);
            *(uint2*)&xl[rloc * 136 + ct + 4] = pk;
        }
        // A2 frags (h1, full K) — xl rows complete for this wave
#pragma unroll
        for (int s = 0; s < 4; ++s) {
            a0[s] = *(const mgn_sh8*)&xl[arow0 + s * 32 + q * 8];
            a1[s] = *(const mgn_sh8*)&xl[arow1 + s * 32 + q * 8];
        }
        {   // acc init: b2 cols ct..ct+3
            float4 bb = *(const float4*)(B2 + d * NDIMC + ct);
            acc0[0] = (mgn_f32x4){bb.x, bb.x, bb.x, bb.x};
            acc0[1] = (mgn_f32x4){bb.y, bb.y, bb.y, bb.y};
            acc0[2] = (mgn_f32x4){bb.z, bb.z, bb.z, bb.z};
            acc0[3] = (mgn_f32x4){bb.w, bb.w, bb.w, bb.w};
            acc1[0] = acc0[0]; acc1[1] = acc0[1]; acc1[2] = acc0[2]; acc1[3] = acc0[3];
        }
        __syncthreads();
        // ---- ph4: stage W2 qd1->B | W2 qd0 (nh0,h0) from A
        mgn_stage_q<BW>(pw2 + 4096, wqB, tid);
        mgn_qcompN(wqA, l, a0 + 0, a1 + 0, acc0, acc1);
        __syncthreads();
        // ---- ph5: stage W2 qd2->A | W2 qd1 (nh0,h1) from B; h2-nh0 stash (bf16); acc -> nh1
        mgn_stage_q<BW>(pw2 + 8192, wqA, tid);
        mgn_qcompN(wqB, l, a0 + 2, a1 + 2, acc0, acc1);
#pragma unroll
        for (int rr = 0; rr < 8; ++rr) {
            const int rloc = wbase + (rr >> 2) * 16 + q * 4 + (rr & 3);
            const int r = rr & 3;
            float v0 = fmaxf((rr < 4) ? acc0[0][r] : acc1[0][r], 0.f);
            float v1 = fmaxf((rr < 4) ? acc0[1][r] : acc1[1][r], 0.f);
            float v2 = fmaxf((rr < 4) ? acc0[2][r] : acc1[2][r], 0.f);
            float v3 = fmaxf((rr < 4) ? acc0[3][r] : acc1[3][r], 0.f);
            uint2 pk; pk.x = mgn_pk(v0, v1); pk.y = mgn_pk(v2, v3);
            *(uint2*)&xl[rloc * 136 + ct] = pk;   // h1 fully consumed into a-regs
        }
        {   // acc init: b2 cols ct+4..ct+7
            float4 bb = *(const float4*)(B2 + d * NDIMC + ct + 4);
            acc0[0] = (mgn_f32x4){bb.x, bb.x, bb.x, bb.x};
            acc0[1] = (mgn_f32x4){bb.y, bb.y, bb.y, bb.y};
            acc0[2] = (mgn_f32x4){bb.z, bb.z, bb.z, bb.z};
            acc0[3] = (mgn_f32x4){bb.w, bb.w, bb.w, bb.w};
            acc1[0] = acc0[0]; acc1[1] = acc0[1]; acc1[2] = acc0[2]; acc1[3] = acc0[3];
        }
        __syncthreads();
        // ---- ph6: stage W2 qd3->B | W2 qd2 (nh1,h0) from A
        mgn_stage_q<BW>(pw2 + 12288, wqB, tid);
        mgn_qcompN(wqA, l, a0 + 0, a1 + 0, acc0, acc1);
        __syncthreads();
        // ---- ph7: stage next-depth W1 qd0->A | W2 qd3 (nh1,h1) from B; LN epilogue
        if (d + 1 < DEPTHC)
            mgn_stage_q<BW>(PW1 + (size_t)(d + 1) * 16384, wqA, tid);
        mgn_qcompN(wqB, l, a0 + 2, a1 + 2, acc0, acc1);

        {
            float4 ga  = *(const float4*)(G  + d * NDIMC + ct);
            float4 gb  = *(const float4*)(G  + d * NDIMC + ct + 4);
            float4 bta = *(const float4*)(BT + d * NDIMC + ct);
            float4 btb = *(const float4*)(BT + d * NDIMC + ct + 4);
            float gv[8]  = {ga.x, ga.y, ga.z, ga.w, gb.x, gb.y, gb.z, gb.w};
            float btv[8] = {bta.x, bta.y, bta.z, bta.w, btb.x, btb.y, btb.z, btb.w};
#pragma unroll
            for (int rr = 0; rr < 8; ++rr) {
                const int rloc = wbase + (rr >> 2) * 16 + q * 4 + (rr & 3);
                const int r = rr & 3;
                float h2[8];
                uint2 st = *(const uint2*)&xl[rloc * 136 + ct];   // relu'd nh0 (bf16)
                h2[0] = __uint_as_float(st.x << 16);
                h2[1] = __uint_as_float(st.x & 0xffff0000u);
                h2[2] = __uint_as_float(st.y << 16);
                h2[3] = __uint_as_float(st.y & 0xffff0000u);
#pragma unroll
                for (int t = 0; t < 4; ++t)
                    h2[4 + t] = fmaxf((rr < 4) ? acc0[t][r] : acc1[t][r], 0.f);
                // single-pass sum & sumsq; independent shfl chains overlap
                float sum = 0.f, ssq = 0.f;
#pragma unroll
                for (int t = 0; t < 8; ++t) {
                    sum += h2[t];
                    ssq = fmaf(h2[t], h2[t], ssq);
                }
                sum += __shfl_xor(sum, 1); ssq += __shfl_xor(ssq, 1);
                sum += __shfl_xor(sum, 2); ssq += __shfl_xor(ssq, 2);
                sum += __shfl_xor(sum, 4); ssq += __shfl_xor(ssq, 4);
                sum += __shfl_xor(sum, 8); ssq += __shfl_xor(ssq, 8);
                float mean = sum * 0.0078125f;
                float var  = fmaf(-mean, mean, ssq * 0.0078125f);
                float rstd = rsqrtf(var + LNEPS);
#pragma unroll
                for (int t = 0; t < 8; ++t) {
                    float at = rstd * gv[t];
                    float ctt = fmaf(-mean, at, btv[t]);
                    xres[rr][t] += fmaf(h2[t], at, ctt);
                }
                if (d != DEPTHC - 1) {
                    uint4 pk;
                    pk.x = mgn_pk(xres[rr][0], xres[rr][1]);
                    pk.y = mgn_pk(xres[rr][2], xres[rr][3]);
                    pk.z = mgn_pk(xres[rr][4], xres[rr][5]);
                    pk.w = mgn_pk(xres[rr][6], xres[rr][7]);
                    *(uint4*)&xl[rloc * 136 + ct] = pk;
                }
            }
        }
        if (d + 1 < DEPTHC) __syncthreads();   // next-depth Q0 visible in wqA
    }

    // ---- tile store
#pragma unroll
    for (int rr = 0; rr < 8; ++rr) {
        const int rloc = wbase + (rr >> 2) * 16 + q * 4 + (rr & 3);
        long gr = rowbase + rloc;
        if (gr < nrows) {
            if (MODE == 1) {
                uint4 pk;
                pk.x = mgn_pk(xres[rr][0], xres[rr][1]);
                pk.y = mgn_pk(xres[rr][2], xres[rr][3]);
                pk.z = mgn_pk(xres[rr][4], xres[rr][5]);
                pk.w = mgn_pk(xres[rr][6], xres[rr][7]);
                *(uint4*)(Eb + (size_t)gr * NDIMC + ct) = pk;
            } else {
                float4 o0 = {xres[rr][0], xres[rr][1], xres[rr][2], xres[rr][3]};
                float4 o1 = {xres[rr][4], xres[rr][5], xres[rr][6], xres[rr][7]};
                *(float4*)(Xf + gr * NDIMC + ct)     = o0;
                *(float4*)(Xf + gr * NDIMC + ct + 4) = o1;
            }
        }
    }
}

// ---------------------------------------------------------------------------
extern "C" void kernel_launch(void* const* d_in, const int* in_sizes, int n_in,
                              void* d_out, int out_size, void* d_ws, size_t ws_size,
                              hipStream_t stream) {
    const float* v    = (const float*)d_in[0];
    const int*   ij   = (const int*)d_in[1];
    const float* encW = (const float*)d_in[2];
    const float* encB = (const float*)d_in[3];
    const float* eW1  = (const float*)d_in[4];
    const float* eB1  = (const float*)d_in[5];
    const float* eW2  = (const float*)d_in[6];
    const float* eB2  = (const float*)d_in[7];
    const float* eG   = (const float*)d_in[8];
    const float* eBT  = (const float*)d_in[9];
    const float* nW1  = (const float*)d_in[10];
    const float* nB1  = (const float*)d_in[11];
    const float* nW2  = (const float*)d_in[12];
    const float* nB2  = (const float*)d_in[13];
    const float* nG   = (const float*)d_in[14];
    const float* nBT  = (const float*)d_in[15];
    const float* decW = (const float*)d_in[16];
    const float* decB = (const float*)d_in[17];
    float* out = (float*)d_out;

    char* ws = (char*)d_ws;
    float*          h    = (float*)(ws + H_OFF);
    unsigned short* ebuf = (unsigned short*)(ws + E_OFF);
    unsigned short* pw   = (unsigned short*)(ws + PW_OFF);
    int*            flag = (int*)(ws + FLAG_OFF);
    int*            deg  = (int*)(ws + DEG_OFF);
    int*            rstt = (int*)(ws + RS_OFF);
    int*            curs = (int*)(ws + CUR_OFF);
    int*            eidx = (int*)(ws + EIDX_OFF);

    mgn_detect_kernel<<<1, 256, 0, stream>>>(ij, flag);
    mgn_pack_kernel<<<(PWMAT + 255) / 256, 256, 0, stream>>>(eW1, pw + 0 * PWMAT);
    mgn_pack_kernel<<<(PWMAT + 255) / 256, 256, 0, stream>>>(eW2, pw + 1 * PWMAT);
    mgn_pack_kernel<<<(PWMAT + 255) / 256, 256, 0, stream>>>(nW1, pw + 2 * PWMAT);
    mgn_pack_kernel<<<(PWMAT + 255) / 256, 256, 0, stream>>>(nW2, pw + 3 * PWMAT);

    // CSR build (static graph; rebuilt every call for graph-capture safety)
    hipMemsetAsync(deg, 0, (size_t)(NNODES + 1) * sizeof(int), stream);
    mgn_deg_kernel<<<(NEDGES + 255) / 256, 256, 0, stream>>>(ij, flag, deg);
    mgn_scan_kernel<<<1, 256, 0, stream>>>(deg, rstt, curs);
    mgn_fill_kernel<<<(NEDGES + 255) / 256, 256, 0, stream>>>(ij, flag, curs, eidx);

    mgn_encoder_kernel<<<(NNODES * NDIMC + 255) / 256, 256, 0, stream>>>(v, encW, encB, h);

    for (int p = 0; p < NPASSESC; ++p) {
        // edge MLP (fused gather; e in CSR-slot order; 128 rows/block)
        mgn_mlp6_mfma_kernel<1, 4><<<NEDGES / 128, 256, 0, stream>>>(
            nullptr, ebuf, h, ij, flag, nullptr, eidx, p > 0 ? 1 : 0, NEDGES,
            pw + 0 * PWMAT, pw + 1 * PWMAT, eB1, eB2, eG, eBT);
        // node MLP with fused CSR aggregation (contiguous Eb reads; 128 rows/block)
        mgn_mlp6_mfma_kernel<0, 4><<<(NNODES + 127) / 128, 256, 0, stream>>>(
            h, ebuf, nullptr, nullptr, nullptr, rstt, nullptr, 0, NNODES,
            pw + 2 * PWMAT, pw + 3 * PWMAT, nB1, nB2, nG, nBT);
    }

    mgn_decoder_kernel<<<(NNODES * NODEIN + 255) / 256, 256, 0, stream>>>(h, decW, decB, out);
}